// Round 3
// baseline (118.587 us; speedup 1.0000x reference)
//
#include <hip/hip_runtime.h>
#include <hip/hip_fp16.h>

// L=8 layers, H=512, K=16 links, N_IN=512, B=8192; out = last 512 cols (fp32).
#define LAYERS 8
#define H      512
#define K      16
#define N_IN   512
#define BATCH  8192
#define R      8      // batch rows per block; 8 x f16 = 16 B -> one ds_read_b128 per gather
#define NT     512    // 8 waves/block; 64 KB LDS -> 2 blocks/CU -> 16 waves/CU
// Layer l gathers from cols [0, 512+512*l); max l=7 -> cols < 4096. Layer 7's
// output is never gathered -> straight to global. LDS = 4096*16 B = 64 KB.
#define LDS_COLS 4096
#define PARAM_N  (LAYERS * H * K)   // 65536 params

// NOTE (R3/R4): NT=1024 variants spill regardless of __launch_bounds__. Stay 512.
// R5: gathers are LDS-bank-conflict-bound (8.67M conflict cycles ~= 8.3/read).
// Fix: per-(l,h) reorder of the 16 links by bank-group (idx&7), staggered by
// (h&15); indices pre-scaled (<<4 = byte offset) to drop the per-gather shift.
// R6: infra timeout, no data. R7: "container failed twice" -- suspect unchecked
// d_ws writes (prep kernel) faulting when ws_size < 512KB. Guard: only use the
// permuted path when ws_size is sufficient; otherwise run the proven baseline
// path (same kernel, template flag, in-kernel shift).

// ---- setup kernel: sort links by bank-group, stagger, pre-scale ----
__global__ __launch_bounds__(512)
void ffn_prep_kernel(const int*   __restrict__ link_idx,
                     const float* __restrict__ weights,
                     int*         __restrict__ idx2,
                     float*       __restrict__ w2)
{
    const int t    = blockIdx.x * 512 + threadIdx.x;   // t = l*H + h  (< LAYERS*H)
    const int base = t * K;

    int idx[K]; float w[K];
    #pragma unroll
    for (int k = 0; k < K; ++k) { idx[k] = link_idx[base + k]; w[k] = weights[base + k]; }

    // counting sort by bank-group p = idx & 7 (16-B block position within 128 B)
    int cnt[8];
    #pragma unroll
    for (int p = 0; p < 8; ++p) cnt[p] = 0;
    #pragma unroll
    for (int k = 0; k < K; ++k) cnt[idx[k] & 7]++;
    int ofs[8]; int s = 0;
    #pragma unroll
    for (int p = 0; p < 8; ++p) { ofs[p] = s; s += cnt[p]; }
    int sid[K]; float sw[K];
    #pragma unroll
    for (int k = 0; k < K; ++k) {
        const int p = idx[k] & 7;
        const int d = ofs[p]++;
        sid[d] = idx[k]; sw[d] = w[k];
    }

    // stagger: lane-class (h & 15) rotates the visit order so every 16-lane
    // group covers all 16 sorted ranks (=> ~2 reads per bank-group) each step.
    const int rot = t & 15;
    #pragma unroll
    for (int j = 0; j < K; ++j) {
        const int srcslot = (j + rot) & 15;
        idx2[base + j] = sid[srcslot] << 4;   // pre-scaled byte offset into vals
        w2[base + j]  = sw[srcslot];
    }
}

// PRESCALED=1: idx array holds byte offsets (permuted path).
// PRESCALED=0: idx array is raw link_idx (baseline path, shift in-kernel).
template <int PRESCALED>
__global__ __launch_bounds__(NT, 2)
void ffn_fused_kernel(const float* __restrict__ x,
                      const int*   __restrict__ idxp,
                      const float* __restrict__ wp,
                      const float* __restrict__ bias,
                      float*       __restrict__ out)
{
    // vals[c*R + r] = f16 value of column c, block batch-row r.
    __shared__ __align__(16) __half vals[LDS_COLS * R];   // 65536 B

    const int tid  = threadIdx.x;
    const int row0 = blockIdx.x * R;

    // ---- Stage x rows into LDS as f16 (each thread owns one column) ----
    {
        const int c = tid;                     // NT == N_IN == 512
        float v[R];
        #pragma unroll
        for (int r = 0; r < R; ++r)
            v[r] = x[(row0 + r) * N_IN + c];   // coalesced per r
        __half2 p[R / 2];
        #pragma unroll
        for (int r = 0; r < R / 2; ++r)
            p[r] = __floats2half2_rn(v[2 * r], v[2 * r + 1]);
        *(uint4*)&vals[c * R] = *(const uint4*)p;   // one ds_write_b128
    }

    // ---- Preload layer-0 params while LDS staging drains (before barrier) ----
    int   idxA[K]; float wA[K]; float bA;
    {
        const int base = tid * K;              // l=0, h=tid
        #pragma unroll
        for (int q = 0; q < 4; ++q) {
            *(int4*)  &idxA[4 * q] = ((const int4*)  (idxp + base))[q];
            *(float4*)&wA  [4 * q] = ((const float4*)(wp   + base))[q];
        }
        if (!PRESCALED) {
            #pragma unroll
            for (int k = 0; k < K; ++k) idxA[k] <<= 4;
        }
        bA = bias[tid];
    }

    __syncthreads();

    // ---- Layers (each thread owns one h; 8 batch rows in registers) ----
    #pragma unroll
    for (int l = 0; l < LAYERS; ++l) {
        // Prefetch next layer's params under this layer's gather/FMA work.
        int idxB[K]; float wB[K]; float bB = 0.0f;
        if (l < LAYERS - 1) {
            const int nb = ((l + 1) * H + tid) * K;
            #pragma unroll
            for (int q = 0; q < 4; ++q) {
                *(int4*)  &idxB[4 * q] = ((const int4*)  (idxp + nb))[q];
                *(float4*)&wB  [4 * q] = ((const float4*)(wp   + nb))[q];
            }
            if (!PRESCALED) {
                #pragma unroll
                for (int k = 0; k < K; ++k) idxB[k] <<= 4;
            }
            bB = bias[(l + 1) * H + tid];
        }

        float acc[R];
        #pragma unroll
        for (int r = 0; r < R; ++r) acc[r] = bA;

        #pragma unroll
        for (int k = 0; k < K; ++k) {
            // one ds_read_b128 = 8 rows of the gathered column (idxA is a byte offset)
            const uint4 g = *(const uint4*)((const char*)vals + idxA[k]);
            const __half2* hp = (const __half2*)&g;
            const float wk = wA[k];
            #pragma unroll
            for (int r = 0; r < R / 2; ++r) {
                const float2 f = __half22float2(hp[r]);   // folds into v_fma_mix_f32
                acc[2 * r]     = fmaf(f.x, wk, acc[2 * r]);
                acc[2 * r + 1] = fmaf(f.y, wk, acc[2 * r + 1]);
            }
        }

        // sigmoid via v_rcp_f32 (~1 ulp) instead of the ~10-instr exact divide
        #pragma unroll
        for (int r = 0; r < R; ++r)
            acc[r] = __builtin_amdgcn_rcpf(1.0f + __expf(-acc[r]));

        if (l < LAYERS - 1) {
            __half2 p[R / 2];
            #pragma unroll
            for (int r = 0; r < R / 2; ++r)
                p[r] = __floats2half2_rn(acc[2 * r], acc[2 * r + 1]);
            *(uint4*)&vals[(N_IN + l * H + tid) * R] = *(const uint4*)p;
            __syncthreads();
            // rotate prefetched params in (full unroll -> register renaming, no moves)
            #pragma unroll
            for (int k = 0; k < K; ++k) { idxA[k] = idxB[k]; wA[k] = wB[k]; }
            bA = bB;
        } else {
            // final layer: coalesced fp32 stores (lanes -> consecutive h)
            #pragma unroll
            for (int r = 0; r < R; ++r)
                out[(row0 + r) * H + tid] = acc[r];
        }
    }
}

extern "C" void kernel_launch(void* const* d_in, const int* in_sizes, int n_in,
                              void* d_out, int out_size, void* d_ws, size_t ws_size,
                              hipStream_t stream) {
    const float* x        = (const float*)d_in[0];
    const int*   link_idx = (const int*)  d_in[1];
    const float* weights  = (const float*)d_in[2];
    const float* bias     = (const float*)d_in[3];
    float*       out      = (float*)d_out;

    const size_t need = 2 * (size_t)PARAM_N * 4;   // idx2 + w2 = 512 KB

    if (d_ws != nullptr && ws_size >= need) {
        int*   idx2 = (int*)d_ws;
        float* w2   = (float*)((char*)d_ws + PARAM_N * sizeof(int));
        ffn_prep_kernel<<<dim3(LAYERS), dim3(512), 0, stream>>>(link_idx, weights, idx2, w2);
        ffn_fused_kernel<1><<<dim3(BATCH / R), dim3(NT), 0, stream>>>(x, idx2, w2, bias, out);
    } else {
        // workspace too small: proven baseline path, no global side-buffers
        ffn_fused_kernel<0><<<dim3(BATCH / R), dim3(NT), 0, stream>>>(x, link_idx, weights, bias, out);
    }
}

// Round 4
// 108.863 us; speedup vs baseline: 1.0893x; 1.0893x over previous
//
#include <hip/hip_runtime.h>
#include <hip/hip_fp16.h>

// L=8 layers, H=512, K=16 links, N_IN=512, B=8192; out = last 512 cols (fp32).
#define LAYERS 8
#define H      512
#define K      16
#define N_IN   512
#define BATCH  8192
#define R      8      // batch rows per block; 8 x f16 = 16 B -> one ds_read_b128 per gather
#define NT     512    // 8 waves/block; 64 KB LDS -> 2 blocks/CU -> 16 waves/CU
// Layer l gathers from cols [0, 512+512*l); max l=7 -> cols < 4096. Layer 7's
// output is never gathered -> straight to global. LDS = 4096*16 B = 64 KB.
#define LDS_COLS 4096

// History:
//  R3/R4: NT=1024 spills regardless of __launch_bounds__. Stay at NT=512.
//  R5/R7: bank-group sort+stagger prep only cut conflicts 12% (LDS arbiter
//    packs lanes dynamically; only the global 64-lane histogram matters, and
//    static permutations don't debias a multinomial). The separate 8-block
//    prep dispatch cost ~10us e2e -- net regression. Reverted to 1 dispatch.
//  R8 (this): LDS pipe only ~65% busy at VGPR=64 (1-2 reads in flight/wave).
//    Occupancy is LDS-bound (2 blocks/CU), so VGPR up to 128 is free:
//    register-double-buffer the gathers (2 batches of 4 ds_read_b128 in
//    flight), __launch_bounds__(512,4) pins the 128-VGPR/2-block point.

__global__ __launch_bounds__(NT, 4)
void ffn_fused_kernel(const float* __restrict__ x,
                      const int*   __restrict__ link_idx,
                      const float* __restrict__ weights,
                      const float* __restrict__ bias,
                      float*       __restrict__ out)
{
    // vals[c*R + r] = f16 value of column c, block batch-row r.
    __shared__ __align__(16) __half vals[LDS_COLS * R];   // 65536 B

    const int tid  = threadIdx.x;
    const int row0 = blockIdx.x * R;

    // ---- Stage x rows into LDS as f16 (each thread owns one column) ----
    {
        const int c = tid;                     // NT == N_IN == 512
        float v[R];
        #pragma unroll
        for (int r = 0; r < R; ++r)
            v[r] = x[(row0 + r) * N_IN + c];   // coalesced per r
        __half2 p[R / 2];
        #pragma unroll
        for (int r = 0; r < R / 2; ++r)
            p[r] = __floats2half2_rn(v[2 * r], v[2 * r + 1]);
        *(uint4*)&vals[c * R] = *(const uint4*)p;   // one ds_write_b128
    }

    // ---- Preload layer-0 params while LDS staging drains (before barrier) ----
    int   idxA[K]; float wA[K]; float bA;
    {
        const int base = tid * K;              // l=0, h=tid
        #pragma unroll
        for (int q = 0; q < 4; ++q) {
            *(int4*)  &idxA[4 * q] = ((const int4*)  (link_idx + base))[q];
            *(float4*)&wA  [4 * q] = ((const float4*)(weights  + base))[q];
        }
        #pragma unroll
        for (int k = 0; k < K; ++k) idxA[k] <<= 4;   // byte offsets once per layer
        bA = bias[tid];
    }

    __syncthreads();

    // ---- Layers (each thread owns one h; 8 batch rows in registers) ----
    #pragma unroll
    for (int l = 0; l < LAYERS; ++l) {
        // Prefetch next layer's params under this layer's gather/FMA work.
        int idxB[K]; float wB[K]; float bB = 0.0f;
        if (l < LAYERS - 1) {
            const int nb = ((l + 1) * H + tid) * K;
            #pragma unroll
            for (int q = 0; q < 4; ++q) {
                *(int4*)  &idxB[4 * q] = ((const int4*)  (link_idx + nb))[q];
                *(float4*)&wB  [4 * q] = ((const float4*)(weights  + nb))[q];
            }
            #pragma unroll
            for (int k = 0; k < K; ++k) idxB[k] <<= 4;
            bB = bias[(l + 1) * H + tid];
        }

        float acc[R];
        #pragma unroll
        for (int r = 0; r < R; ++r) acc[r] = bA;

        // ---- Gather pipeline: 2 register buffers x 4 ds_read_b128 in flight.
        // All indices are known up-front, so batch n+1's reads issue before
        // batch n's FMAs consume -> LDS pipe stays fed instead of ping-pong
        // read->wait->fma. kb is compile-time (full unroll): g[] indexing is
        // static, no scratch (rule: runtime-indexed arrays spill).
        uint4 g[2][4];
        #pragma unroll
        for (int j = 0; j < 4; ++j)
            g[0][j] = *(const uint4*)((const char*)vals + idxA[j]);

        #pragma unroll
        for (int kb = 0; kb < K; kb += 4) {
            const int cur = (kb >> 2) & 1;
            const int nxt = cur ^ 1;
            if (kb + 4 < K) {
                #pragma unroll
                for (int j = 0; j < 4; ++j)
                    g[nxt][j] = *(const uint4*)((const char*)vals + idxA[kb + 4 + j]);
            }
            #pragma unroll
            for (int j = 0; j < 4; ++j) {
                const __half2* hp = (const __half2*)&g[cur][j];
                const float wk = wA[kb + j];
                #pragma unroll
                for (int r = 0; r < R / 2; ++r) {
                    const float2 f = __half22float2(hp[r]);   // folds into v_fma_mix_f32
                    acc[2 * r]     = fmaf(f.x, wk, acc[2 * r]);
                    acc[2 * r + 1] = fmaf(f.y, wk, acc[2 * r + 1]);
                }
            }
        }

        // sigmoid via v_rcp_f32 (~1 ulp) instead of the ~10-instr exact divide
        #pragma unroll
        for (int r = 0; r < R; ++r)
            acc[r] = __builtin_amdgcn_rcpf(1.0f + __expf(-acc[r]));

        if (l < LAYERS - 1) {
            __half2 p[R / 2];
            #pragma unroll
            for (int r = 0; r < R / 2; ++r)
                p[r] = __floats2half2_rn(acc[2 * r], acc[2 * r + 1]);
            *(uint4*)&vals[(N_IN + l * H + tid) * R] = *(const uint4*)p;
            __syncthreads();
            // rotate prefetched params in (full unroll -> register renaming, no moves)
            #pragma unroll
            for (int k = 0; k < K; ++k) { idxA[k] = idxB[k]; wA[k] = wB[k]; }
            bA = bB;
        } else {
            // final layer: coalesced fp32 stores (lanes -> consecutive h)
            #pragma unroll
            for (int r = 0; r < R; ++r)
                out[(row0 + r) * H + tid] = acc[r];
        }
    }
}

extern "C" void kernel_launch(void* const* d_in, const int* in_sizes, int n_in,
                              void* d_out, int out_size, void* d_ws, size_t ws_size,
                              hipStream_t stream) {
    const float* x        = (const float*)d_in[0];
    const int*   link_idx = (const int*)  d_in[1];
    const float* weights  = (const float*)d_in[2];
    const float* bias     = (const float*)d_in[3];
    float*       out      = (float*)d_out;

    ffn_fused_kernel<<<dim3(BATCH / R), dim3(NT), 0, stream>>>(x, link_idx, weights, bias, out);
}